// Round 1
// baseline (5688.188 us; speedup 1.0000x reference)
//
#include <hip/hip_runtime.h>

#define DIM 256
#define ALPHA 0.1f
#define TM 32
#define KC 32

// ---------------- degree ----------------
__global__ void deg_kernel(const int* __restrict__ dst, int E, int* __restrict__ deg) {
    int e = blockIdx.x * blockDim.x + threadIdx.x;
    if (e < E) atomicAdd(&deg[dst[e]], 1);
}

__global__ void invdeg_kernel(const int* __restrict__ deg, int N, float* __restrict__ inv_deg) {
    int n = blockIdx.x * blockDim.x + threadIdx.x;
    if (n < N) inv_deg[n] = 1.0f / (float)max(deg[n], 1);
}

// ---------------- scatter-add aggregation ----------------
// one thread per (edge, 4-float chunk); 64 chunks cover DIM=256
__global__ void scatter_kernel(const float* __restrict__ x,
                               const int* __restrict__ src,
                               const int* __restrict__ dst,
                               int E, float* __restrict__ agg) {
    int idx = blockIdx.x * blockDim.x + threadIdx.x;
    int e = idx >> 6;
    if (e >= E) return;
    int c = (idx & 63) << 2;
    int s = src[e];
    int d = dst[e];
    const float4 v = *(const float4*)(x + (size_t)s * DIM + c);
    float* p = agg + (size_t)d * DIM + c;
    atomicAdd(p + 0, v.x);
    atomicAdd(p + 1, v.y);
    atomicAdd(p + 2, v.z);
    atomicAdd(p + 3, v.w);
}

// ---------------- fused residual + GEMM + relu ----------------
// out[n,j] = relu( sum_k (ALPHA*x0[n,k] + (1-ALPHA)*inv_deg[n]*agg[n,k]) * W[k,j] )
// block = 256 threads, tile = TM(32) rows x DIM(256) cols.
// thread t: rows (t>>6)*8 .. +8, cols (t&63)*4 .. +4  -> acc[8][4]
__global__ __launch_bounds__(256) void gemm_kernel(
    const float* __restrict__ agg, const float* __restrict__ x0,
    const float* __restrict__ inv_deg, const float* __restrict__ W,
    float* __restrict__ out, int N)
{
    __shared__ __align__(16) float Wl[KC][DIM];  // 32 KB
    __shared__ __align__(16) float Hl[TM][KC];   // 4 KB

    const int t    = threadIdx.x;
    const int row0 = blockIdx.x * TM;
    const int lane = t & 63;
    const int wid  = t >> 6;
    const int jc   = lane * 4;   // output col base
    const int r0   = wid * 8;    // output row base (within tile)

    // h-tile load mapping: thread t loads Hl[t>>3][(t&7)*4 .. +4]
    const int hr   = t >> 3;
    const int hk   = (t & 7) * 4;
    const int hrow = row0 + hr;
    const float id = (hrow < N) ? inv_deg[hrow] : 0.0f;

    float acc[8][4];
    #pragma unroll
    for (int r = 0; r < 8; r++)
        #pragma unroll
        for (int c = 0; c < 4; c++) acc[r][c] = 0.0f;

    for (int kb = 0; kb < DIM; kb += KC) {
        // stage W[kb:kb+KC][:] -> LDS (contiguous KC*DIM floats)
        const float* wsrc = W + (size_t)kb * DIM;
        float* wdst = &Wl[0][0];
        #pragma unroll
        for (int i = 0; i < (KC * DIM) / (256 * 4); i++) {
            int fl = i * 1024 + t * 4;
            *(float4*)(wdst + fl) = *(const float4*)(wsrc + fl);
        }
        // stage fused h tile -> LDS
        float4 h;
        if (hrow < N) {
            float4 a = *(const float4*)(agg + (size_t)hrow * DIM + kb + hk);
            float4 x = *(const float4*)(x0  + (size_t)hrow * DIM + kb + hk);
            h.x = ALPHA * x.x + (1.0f - ALPHA) * id * a.x;
            h.y = ALPHA * x.y + (1.0f - ALPHA) * id * a.y;
            h.z = ALPHA * x.z + (1.0f - ALPHA) * id * a.z;
            h.w = ALPHA * x.w + (1.0f - ALPHA) * id * a.w;
        } else {
            h.x = h.y = h.z = h.w = 0.0f;
        }
        *(float4*)&Hl[hr][hk] = h;
        __syncthreads();

        // inner product: k unrolled by 4 to amortize LDS reads
        #pragma unroll
        for (int k = 0; k < KC; k += 4) {
            float4 h4[8];
            #pragma unroll
            for (int r = 0; r < 8; r++)
                h4[r] = *(const float4*)&Hl[r0 + r][k];
            #pragma unroll
            for (int kk = 0; kk < 4; kk++) {
                float4 w = *(const float4*)&Wl[k + kk][jc];
                #pragma unroll
                for (int r = 0; r < 8; r++) {
                    float hv = (&h4[r].x)[kk];
                    acc[r][0] += hv * w.x;
                    acc[r][1] += hv * w.y;
                    acc[r][2] += hv * w.z;
                    acc[r][3] += hv * w.w;
                }
            }
        }
        __syncthreads();
    }

    #pragma unroll
    for (int r = 0; r < 8; r++) {
        int row = row0 + r0 + r;
        if (row < N) {
            float4 o;
            o.x = fmaxf(acc[r][0], 0.0f);
            o.y = fmaxf(acc[r][1], 0.0f);
            o.z = fmaxf(acc[r][2], 0.0f);
            o.w = fmaxf(acc[r][3], 0.0f);
            *(float4*)(out + (size_t)row * DIM + jc) = o;
        }
    }
}

extern "C" void kernel_launch(void* const* d_in, const int* in_sizes, int n_in,
                              void* d_out, int out_size, void* d_ws, size_t ws_size,
                              hipStream_t stream) {
    const float* x0  = (const float*)d_in[0];
    const int*   ei  = (const int*)d_in[1];
    const float* W   = (const float*)d_in[2];
    float*       out = (float*)d_out;

    const int N = in_sizes[0] / DIM;
    const int E = in_sizes[1] / 2;
    const int* src = ei;
    const int* dst = ei + E;

    char* ws = (char*)d_ws;
    float* agg     = (float*)ws;                                   // N*DIM floats
    float* inv_deg = (float*)(ws + (size_t)N * DIM * 4);           // N floats
    int*   deg     = (int*)  (ws + (size_t)N * DIM * 4 + (size_t)N * 4);  // N ints

    // degree (edge-structure invariant; computed every launch as required)
    hipMemsetAsync(deg, 0, (size_t)N * 4, stream);
    deg_kernel<<<(E + 255) / 256, 256, 0, stream>>>(dst, E, deg);
    invdeg_kernel<<<(N + 255) / 256, 256, 0, stream>>>(deg, N, inv_deg);

    const float* xcur = x0;
    for (int layer = 0; layer < 5; layer++) {
        hipMemsetAsync(agg, 0, (size_t)N * DIM * 4, stream);
        long long total = (long long)E * 64;
        scatter_kernel<<<(int)((total + 255) / 256), 256, 0, stream>>>(xcur, src, dst, E, agg);
        gemm_kernel<<<(N + TM - 1) / TM, 256, 0, stream>>>(agg, x0, inv_deg, W, out, N);
        xcur = out;  // next layer aggregates from this layer's output (safe: same stream)
    }
}

// Round 2
// 919.637 us; speedup vs baseline: 6.1853x; 6.1853x over previous
//
#include <hip/hip_runtime.h>

#define DIM 256
#define ALPHA 0.1f
#define TM 32
#define KC 32
#define SCAN_B 256

// ---------------- degree histogram ----------------
__global__ void deg_kernel(const int* __restrict__ dst, int E, int* __restrict__ deg) {
    int e = blockIdx.x * blockDim.x + threadIdx.x;
    if (e < E) atomicAdd(&deg[dst[e]], 1);
}

__global__ void invdeg_kernel(const int* __restrict__ deg, int N, float* __restrict__ inv_deg) {
    int n = blockIdx.x * blockDim.x + threadIdx.x;
    if (n < N) inv_deg[n] = 1.0f / (float)max(deg[n], 1);
}

// ---------------- hierarchical exclusive scan (deg -> row_start) ----------------
// covers N+1 virtual elements (deg[i]=0 for i>=N) so row_start[N]=E.
__global__ void scan1_kernel(const int* __restrict__ deg, int N,
                             int* __restrict__ excl, int* __restrict__ bsums) {
    __shared__ int s[SCAN_B];
    int tid = threadIdx.x;
    int i = blockIdx.x * SCAN_B + tid;
    int v = (i < N) ? deg[i] : 0;
    s[tid] = v;
    __syncthreads();
    #pragma unroll
    for (int off = 1; off < SCAN_B; off <<= 1) {
        int t = (tid >= off) ? s[tid - off] : 0;
        __syncthreads();
        s[tid] += t;
        __syncthreads();
    }
    if (i <= N) excl[i] = s[tid] - v;          // exclusive within block
    if (tid == SCAN_B - 1) bsums[blockIdx.x] = s[tid];
}

__global__ void scan2_kernel(int* __restrict__ bsums, int nb) {
    __shared__ int s[SCAN_B];
    int tid = threadIdx.x;
    int v = (tid < nb) ? bsums[tid] : 0;
    s[tid] = v;
    __syncthreads();
    #pragma unroll
    for (int off = 1; off < SCAN_B; off <<= 1) {
        int t = (tid >= off) ? s[tid - off] : 0;
        __syncthreads();
        s[tid] += t;
        __syncthreads();
    }
    if (tid < nb) bsums[tid] = s[tid] - v;     // exclusive block offsets
}

__global__ void scan3_kernel(const int* __restrict__ excl, const int* __restrict__ bsums,
                             int N, int* __restrict__ row_start) {
    int i = blockIdx.x * SCAN_B + threadIdx.x;
    if (i <= N) row_start[i] = excl[i] + bsums[blockIdx.x];
}

// ---------------- CSR bucket fill ----------------
__global__ void fill_kernel(const int* __restrict__ src, const int* __restrict__ dst, int E,
                            const int* __restrict__ row_start, int* __restrict__ cursor,
                            int* __restrict__ csr_src) {
    int e = blockIdx.x * blockDim.x + threadIdx.x;
    if (e < E) {
        int d = dst[e];
        int pos = row_start[d] + atomicAdd(&cursor[d], 1);
        csr_src[pos] = src[e];
    }
}

// ---------------- gather aggregation + residual mix (no atomics) ----------------
// one 64-lane wave per node; lane owns 4 contiguous columns.
// h[n,:] = ALPHA*x0[n,:] + (1-ALPHA)*inv_deg[n]*sum_{e in CSR[n]} x[src_e,:]
__global__ __launch_bounds__(256) void aggregate_kernel(
    const float* __restrict__ x, const float* __restrict__ x0,
    const int* __restrict__ row_start, const int* __restrict__ csr_src,
    const float* __restrict__ inv_deg, float* __restrict__ h, int N)
{
    int node = blockIdx.x * 4 + (threadIdx.x >> 6);
    if (node >= N) return;
    int c = (threadIdx.x & 63) * 4;

    int beg = row_start[node];
    int end = row_start[node + 1];

    float4 acc = make_float4(0.f, 0.f, 0.f, 0.f);
    for (int e = beg; e < end; e++) {
        int s = csr_src[e];
        float4 v = *(const float4*)(x + (size_t)s * DIM + c);
        acc.x += v.x; acc.y += v.y; acc.z += v.z; acc.w += v.w;
    }

    float scale = (1.0f - ALPHA) * inv_deg[node];
    float4 xv = *(const float4*)(x0 + (size_t)node * DIM + c);
    float4 hv;
    hv.x = ALPHA * xv.x + scale * acc.x;
    hv.y = ALPHA * xv.y + scale * acc.y;
    hv.z = ALPHA * xv.z + scale * acc.z;
    hv.w = ALPHA * xv.w + scale * acc.w;
    *(float4*)(h + (size_t)node * DIM + c) = hv;
}

// ---------------- GEMM + relu: out = relu(h @ W) ----------------
// block = 256 threads, tile = TM(32) rows x DIM(256) cols.
__global__ __launch_bounds__(256) void gemm_kernel(
    const float* __restrict__ h, const float* __restrict__ W,
    float* __restrict__ out, int N)
{
    __shared__ __align__(16) float Wl[KC][DIM];  // 32 KB
    __shared__ __align__(16) float Hl[TM][KC];   // 4 KB

    const int t    = threadIdx.x;
    const int row0 = blockIdx.x * TM;
    const int lane = t & 63;
    const int wid  = t >> 6;
    const int jc   = lane * 4;   // output col base
    const int r0   = wid * 8;    // output row base (within tile)

    const int hr   = t >> 3;
    const int hk   = (t & 7) * 4;
    const int hrow = row0 + hr;

    float acc[8][4];
    #pragma unroll
    for (int r = 0; r < 8; r++)
        #pragma unroll
        for (int c = 0; c < 4; c++) acc[r][c] = 0.0f;

    for (int kb = 0; kb < DIM; kb += KC) {
        const float* wsrc = W + (size_t)kb * DIM;
        float* wdst = &Wl[0][0];
        #pragma unroll
        for (int i = 0; i < (KC * DIM) / (256 * 4); i++) {
            int fl = i * 1024 + t * 4;
            *(float4*)(wdst + fl) = *(const float4*)(wsrc + fl);
        }
        float4 hv = make_float4(0.f, 0.f, 0.f, 0.f);
        if (hrow < N) hv = *(const float4*)(h + (size_t)hrow * DIM + kb + hk);
        *(float4*)&Hl[hr][hk] = hv;
        __syncthreads();

        #pragma unroll
        for (int k = 0; k < KC; k += 4) {
            float4 h4[8];
            #pragma unroll
            for (int r = 0; r < 8; r++)
                h4[r] = *(const float4*)&Hl[r0 + r][k];
            #pragma unroll
            for (int kk = 0; kk < 4; kk++) {
                float4 w = *(const float4*)&Wl[k + kk][jc];
                #pragma unroll
                for (int r = 0; r < 8; r++) {
                    float hvv = (&h4[r].x)[kk];
                    acc[r][0] += hvv * w.x;
                    acc[r][1] += hvv * w.y;
                    acc[r][2] += hvv * w.z;
                    acc[r][3] += hvv * w.w;
                }
            }
        }
        __syncthreads();
    }

    #pragma unroll
    for (int r = 0; r < 8; r++) {
        int row = row0 + r0 + r;
        if (row < N) {
            float4 o;
            o.x = fmaxf(acc[r][0], 0.0f);
            o.y = fmaxf(acc[r][1], 0.0f);
            o.z = fmaxf(acc[r][2], 0.0f);
            o.w = fmaxf(acc[r][3], 0.0f);
            *(float4*)(out + (size_t)row * DIM + jc) = o;
        }
    }
}

extern "C" void kernel_launch(void* const* d_in, const int* in_sizes, int n_in,
                              void* d_out, int out_size, void* d_ws, size_t ws_size,
                              hipStream_t stream) {
    const float* x0  = (const float*)d_in[0];
    const int*   ei  = (const int*)d_in[1];
    const float* W   = (const float*)d_in[2];
    float*       out = (float*)d_out;

    const int N = in_sizes[0] / DIM;
    const int E = in_sizes[1] / 2;
    const int* src = ei;
    const int* dst = ei + E;

    const int nb = (N + 1 + SCAN_B - 1) / SCAN_B;   // scan blocks (<=256 required)

    char* ws = (char*)d_ws;
    size_t off = 0;
    auto alloc = [&](size_t bytes) { char* p = ws + off; off += (bytes + 15) & ~size_t(15); return p; };
    float* h        = (float*)alloc((size_t)N * DIM * 4);
    float* inv_deg  = (float*)alloc((size_t)N * 4);
    int*   deg      = (int*)  alloc((size_t)N * 4);
    int*   row_start= (int*)  alloc((size_t)(N + 1) * 4);
    int*   excl     = (int*)  alloc((size_t)(N + 1) * 4);
    int*   cursor   = (int*)  alloc((size_t)N * 4);
    int*   bsums    = (int*)  alloc((size_t)nb * 4);
    int*   csr_src  = (int*)  alloc((size_t)E * 4);

    // ---- CSR build (per launch; edge-structure derived) ----
    hipMemsetAsync(deg, 0, (size_t)N * 4, stream);
    hipMemsetAsync(cursor, 0, (size_t)N * 4, stream);
    deg_kernel<<<(E + 255) / 256, 256, 0, stream>>>(dst, E, deg);
    invdeg_kernel<<<(N + 255) / 256, 256, 0, stream>>>(deg, N, inv_deg);
    scan1_kernel<<<nb, SCAN_B, 0, stream>>>(deg, N, excl, bsums);
    scan2_kernel<<<1, SCAN_B, 0, stream>>>(bsums, nb);
    scan3_kernel<<<nb, SCAN_B, 0, stream>>>(excl, bsums, N, row_start);
    fill_kernel<<<(E + 255) / 256, 256, 0, stream>>>(src, dst, E, row_start, cursor, csr_src);

    // ---- 5 GCN layers ----
    const float* xcur = x0;
    for (int layer = 0; layer < 5; layer++) {
        aggregate_kernel<<<(N + 3) / 4, 256, 0, stream>>>(xcur, x0, row_start, csr_src, inv_deg, h, N);
        gemm_kernel<<<(N + TM - 1) / TM, 256, 0, stream>>>(h, W, out, N);
        xcur = out;
    }
}

// Round 3
// 590.737 us; speedup vs baseline: 9.6290x; 1.5568x over previous
//
#include <hip/hip_runtime.h>

#define DIM 256
#define ALPHA 0.1f
#define SCAN_B 256

typedef __attribute__((ext_vector_type(8))) short short8;
typedef __attribute__((ext_vector_type(4))) float f32x4;

__device__ __forceinline__ unsigned short f32_to_bf16(float x) {
    unsigned int u = __float_as_uint(x);
    unsigned int r = u + 0x7FFFu + ((u >> 16) & 1u);
    return (unsigned short)(r >> 16);
}
__device__ __forceinline__ float bf16_to_f32(unsigned short h) {
    return __uint_as_float(((unsigned int)h) << 16);
}

__device__ __forceinline__ void load_lds16(const void* g, void* l) {
    __builtin_amdgcn_global_load_lds(
        (const __attribute__((address_space(1))) unsigned int*)g,
        (__attribute__((address_space(3))) unsigned int*)l, 16, 0, 0);
}

// ---------------- degree histogram ----------------
__global__ void deg_kernel(const int* __restrict__ dst, int E, int* __restrict__ deg) {
    int e = blockIdx.x * blockDim.x + threadIdx.x;
    if (e < E) atomicAdd(&deg[dst[e]], 1);
}

__global__ void invdeg_kernel(const int* __restrict__ deg, int N, float* __restrict__ inv_deg) {
    int n = blockIdx.x * blockDim.x + threadIdx.x;
    if (n < N) inv_deg[n] = 1.0f / (float)max(deg[n], 1);
}

// ---------------- hierarchical exclusive scan (deg -> row_start) ----------------
__global__ void scan1_kernel(const int* __restrict__ deg, int N,
                             int* __restrict__ excl, int* __restrict__ bsums) {
    __shared__ int s[SCAN_B];
    int tid = threadIdx.x;
    int i = blockIdx.x * SCAN_B + tid;
    int v = (i < N) ? deg[i] : 0;
    s[tid] = v;
    __syncthreads();
    #pragma unroll
    for (int off = 1; off < SCAN_B; off <<= 1) {
        int t = (tid >= off) ? s[tid - off] : 0;
        __syncthreads();
        s[tid] += t;
        __syncthreads();
    }
    if (i <= N) excl[i] = s[tid] - v;
    if (tid == SCAN_B - 1) bsums[blockIdx.x] = s[tid];
}

__global__ void scan2_kernel(int* __restrict__ bsums, int nb) {
    __shared__ int s[SCAN_B];
    int tid = threadIdx.x;
    int v = (tid < nb) ? bsums[tid] : 0;
    s[tid] = v;
    __syncthreads();
    #pragma unroll
    for (int off = 1; off < SCAN_B; off <<= 1) {
        int t = (tid >= off) ? s[tid - off] : 0;
        __syncthreads();
        s[tid] += t;
        __syncthreads();
    }
    if (tid < nb) bsums[tid] = s[tid] - v;
}

__global__ void scan3_kernel(const int* __restrict__ excl, const int* __restrict__ bsums,
                             int N, int* __restrict__ row_start) {
    int i = blockIdx.x * SCAN_B + threadIdx.x;
    if (i <= N) row_start[i] = excl[i] + bsums[blockIdx.x];
}

// ---------------- CSR bucket fill ----------------
__global__ void fill_kernel(const int* __restrict__ src, const int* __restrict__ dst, int E,
                            const int* __restrict__ row_start, int* __restrict__ cursor,
                            int* __restrict__ csr_src) {
    int e = blockIdx.x * blockDim.x + threadIdx.x;
    if (e < E) {
        int d = dst[e];
        int pos = row_start[d] + atomicAdd(&cursor[d], 1);
        csr_src[pos] = src[e];
    }
}

// ---------------- W -> transposed bf16 hi/lo split (once per launch) ----------------
__global__ void wprep_kernel(const float* __restrict__ W,
                             unsigned short* __restrict__ Wt_hi,
                             unsigned short* __restrict__ Wt_lo) {
    int k = blockIdx.x;
    int n = threadIdx.x;
    float w = W[k * DIM + n];
    unsigned short hi = f32_to_bf16(w);
    float rem = w - bf16_to_f32(hi);
    Wt_hi[n * DIM + k] = hi;
    Wt_lo[n * DIM + k] = f32_to_bf16(rem);
}

// ---------------- gather aggregation + residual mix -> bf16 hi/lo h ----------------
__global__ __launch_bounds__(256) void aggregate_kernel(
    const float* __restrict__ x, const float* __restrict__ x0,
    const int* __restrict__ row_start, const int* __restrict__ csr_src,
    const float* __restrict__ inv_deg,
    unsigned short* __restrict__ h_hi, unsigned short* __restrict__ h_lo, int N)
{
    int node = blockIdx.x * 4 + (threadIdx.x >> 6);
    if (node >= N) return;
    int c = (threadIdx.x & 63) * 4;

    int beg = row_start[node];
    int end = row_start[node + 1];

    float4 acc = make_float4(0.f, 0.f, 0.f, 0.f);
    for (int e = beg; e < end; e++) {
        int s = csr_src[e];
        float4 v = *(const float4*)(x + (size_t)s * DIM + c);
        acc.x += v.x; acc.y += v.y; acc.z += v.z; acc.w += v.w;
    }

    float scale = (1.0f - ALPHA) * inv_deg[node];
    float4 xv = *(const float4*)(x0 + (size_t)node * DIM + c);
    float hv[4];
    hv[0] = ALPHA * xv.x + scale * acc.x;
    hv[1] = ALPHA * xv.y + scale * acc.y;
    hv[2] = ALPHA * xv.z + scale * acc.z;
    hv[3] = ALPHA * xv.w + scale * acc.w;

    ushort4 hi4, lo4;
    unsigned short* hip_ = &hi4.x;
    unsigned short* lop_ = &lo4.x;
    #pragma unroll
    for (int i = 0; i < 4; i++) {
        unsigned short hb = f32_to_bf16(hv[i]);
        hip_[i] = hb;
        lop_[i] = f32_to_bf16(hv[i] - bf16_to_f32(hb));
    }
    *(ushort4*)(h_hi + (size_t)node * DIM + c) = hi4;
    *(ushort4*)(h_lo + (size_t)node * DIM + c) = lo4;
}

// ---------------- MFMA GEMM: out = relu(h @ W), bf16x3 split precision ----------------
// 128x128 tile per 256-thread block; 4 waves in 2x2; each wave 4x4 frags of 16x16x32.
__global__ __launch_bounds__(256) void gemm_mfma_kernel(
    const unsigned short* __restrict__ h_hi, const unsigned short* __restrict__ h_lo,
    const unsigned short* __restrict__ Wt_hi, const unsigned short* __restrict__ Wt_lo,
    float* __restrict__ out, int N)
{
    __shared__ unsigned short As_hi[128 * 32];
    __shared__ unsigned short As_lo[128 * 32];
    __shared__ unsigned short Bs_hi[128 * 32];
    __shared__ unsigned short Bs_lo[128 * 32];

    const int t    = threadIdx.x;
    const int w    = t >> 6;
    const int lane = t & 63;
    const int lm   = lane & 15;
    const int q    = lane >> 4;
    const int wm   = w >> 1, wn = w & 1;
    const int m0   = blockIdx.x * 128;
    const int n0   = blockIdx.y * 128;

    // staging assignment: wave w owns one of the four tile halves
    const unsigned short* gsrc;
    unsigned short* lds;
    int row_base;
    if (w == 0)      { gsrc = h_hi;  lds = As_hi; row_base = m0; }
    else if (w == 1) { gsrc = h_lo;  lds = As_lo; row_base = m0; }
    else if (w == 2) { gsrc = Wt_hi; lds = Bs_hi; row_base = n0; }
    else             { gsrc = Wt_lo; lds = Bs_lo; row_base = n0; }
    const int rl = lane >> 2;   // 0..15
    const int g  = lane & 3;    // 16B granule within a 64B row

    f32x4 acc[4][4];
    #pragma unroll
    for (int mi = 0; mi < 4; mi++)
        #pragma unroll
        for (int ni = 0; ni < 4; ni++)
            acc[mi][ni] = (f32x4){0.f, 0.f, 0.f, 0.f};

    for (int kb = 0; kb < DIM; kb += 32) {
        __syncthreads();   // prior compute done before overwriting LDS
        #pragma unroll
        for (int j = 0; j < 8; j++) {
            int r = j * 16 + rl;
            const unsigned short* src = gsrc + (size_t)(row_base + r) * DIM + kb + g * 8;
            load_lds16(src, &lds[j * 512]);
        }
        __syncthreads();   // drains vmcnt -> staged data visible

        short8 a_hi[4], a_lo[4];
        #pragma unroll
        for (int mi = 0; mi < 4; mi++) {
            int row = wm * 64 + mi * 16 + lm;
            a_hi[mi] = *(const short8*)&As_hi[row * 32 + q * 8];
            a_lo[mi] = *(const short8*)&As_lo[row * 32 + q * 8];
        }
        #pragma unroll
        for (int ni = 0; ni < 4; ni++) {
            int row = wn * 64 + ni * 16 + lm;
            short8 b_hi = *(const short8*)&Bs_hi[row * 32 + q * 8];
            short8 b_lo = *(const short8*)&Bs_lo[row * 32 + q * 8];
            #pragma unroll
            for (int mi = 0; mi < 4; mi++) {
                acc[mi][ni] = __builtin_amdgcn_mfma_f32_16x16x32_bf16(a_hi[mi], b_hi, acc[mi][ni], 0, 0, 0);
                acc[mi][ni] = __builtin_amdgcn_mfma_f32_16x16x32_bf16(a_hi[mi], b_lo, acc[mi][ni], 0, 0, 0);
                acc[mi][ni] = __builtin_amdgcn_mfma_f32_16x16x32_bf16(a_lo[mi], b_hi, acc[mi][ni], 0, 0, 0);
            }
        }
    }

    // epilogue: C/D layout col=lane&15, row=q*4+reg
    #pragma unroll
    for (int mi = 0; mi < 4; mi++) {
        const int rowb = m0 + wm * 64 + mi * 16 + q * 4;
        #pragma unroll
        for (int ni = 0; ni < 4; ni++) {
            const int col = n0 + wn * 64 + ni * 16 + lm;
            #pragma unroll
            for (int r = 0; r < 4; r++) {
                int row = rowb + r;
                if (row < N) out[(size_t)row * DIM + col] = fmaxf(acc[mi][ni][r], 0.0f);
            }
        }
    }
}

extern "C" void kernel_launch(void* const* d_in, const int* in_sizes, int n_in,
                              void* d_out, int out_size, void* d_ws, size_t ws_size,
                              hipStream_t stream) {
    const float* x0  = (const float*)d_in[0];
    const int*   ei  = (const int*)d_in[1];
    const float* W   = (const float*)d_in[2];
    float*       out = (float*)d_out;

    const int N = in_sizes[0] / DIM;
    const int E = in_sizes[1] / 2;
    const int N_pad = (N + 127) & ~127;
    const int* src = ei;
    const int* dst = ei + E;

    const int nb = (N + 1 + SCAN_B - 1) / SCAN_B;

    char* ws = (char*)d_ws;
    size_t off = 0;
    auto alloc = [&](size_t bytes) { char* p = ws + off; off += (bytes + 15) & ~size_t(15); return p; };
    unsigned short* h_hi    = (unsigned short*)alloc((size_t)N_pad * DIM * 2);
    unsigned short* h_lo    = (unsigned short*)alloc((size_t)N_pad * DIM * 2);
    unsigned short* Wt_hi   = (unsigned short*)alloc((size_t)DIM * DIM * 2);
    unsigned short* Wt_lo   = (unsigned short*)alloc((size_t)DIM * DIM * 2);
    float* inv_deg  = (float*)alloc((size_t)N * 4);
    int*   deg      = (int*)  alloc((size_t)N * 4);
    int*   row_start= (int*)  alloc((size_t)(N + 1) * 4);
    int*   excl     = (int*)  alloc((size_t)(N + 1) * 4);
    int*   cursor   = (int*)  alloc((size_t)N * 4);
    int*   bsums    = (int*)  alloc((size_t)nb * 4);
    int*   csr_src  = (int*)  alloc((size_t)E * 4);

    // ---- CSR build + W prep (per launch) ----
    hipMemsetAsync(deg, 0, (size_t)N * 4, stream);
    hipMemsetAsync(cursor, 0, (size_t)N * 4, stream);
    deg_kernel<<<(E + 255) / 256, 256, 0, stream>>>(dst, E, deg);
    invdeg_kernel<<<(N + 255) / 256, 256, 0, stream>>>(deg, N, inv_deg);
    scan1_kernel<<<nb, SCAN_B, 0, stream>>>(deg, N, excl, bsums);
    scan2_kernel<<<1, SCAN_B, 0, stream>>>(bsums, nb);
    scan3_kernel<<<nb, SCAN_B, 0, stream>>>(excl, bsums, N, row_start);
    fill_kernel<<<(E + 255) / 256, 256, 0, stream>>>(src, dst, E, row_start, cursor, csr_src);
    wprep_kernel<<<DIM, DIM, 0, stream>>>(W, Wt_hi, Wt_lo);

    // ---- 5 GCN layers ----
    dim3 ggrid(N_pad / 128, 2);
    const float* xcur = x0;
    for (int layer = 0; layer < 5; layer++) {
        aggregate_kernel<<<(N + 3) / 4, 256, 0, stream>>>(xcur, x0, row_start, csr_src,
                                                          inv_deg, h_hi, h_lo, N);
        gemm_mfma_kernel<<<ggrid, 256, 0, stream>>>(h_hi, h_lo, Wt_hi, Wt_lo, out, N);
        xcur = out;
    }
}

// Round 4
// 499.013 us; speedup vs baseline: 11.3989x; 1.1838x over previous
//
#include <hip/hip_runtime.h>

#define DIM 256
#define ALPHA 0.1f
#define SCAN_B 256

typedef __attribute__((ext_vector_type(8))) short short8;
typedef __attribute__((ext_vector_type(4))) float f32x4;

__device__ __forceinline__ unsigned short f32_to_bf16(float x) {
    unsigned int u = __float_as_uint(x);
    unsigned int r = u + 0x7FFFu + ((u >> 16) & 1u);
    return (unsigned short)(r >> 16);
}
__device__ __forceinline__ float bf16_to_f32(unsigned short h) {
    return __uint_as_float(((unsigned int)h) << 16);
}

__device__ __forceinline__ void load_lds16(const void* g, void* l) {
    __builtin_amdgcn_global_load_lds(
        (const __attribute__((address_space(1))) unsigned int*)g,
        (__attribute__((address_space(3))) unsigned int*)l, 16, 0, 0);
}

// ---------------- degree histogram ----------------
__global__ void deg_kernel(const int* __restrict__ dst, int E, int* __restrict__ deg) {
    int e = blockIdx.x * blockDim.x + threadIdx.x;
    if (e < E) atomicAdd(&deg[dst[e]], 1);
}

__global__ void invdeg_kernel(const int* __restrict__ deg, int N, float* __restrict__ inv_deg) {
    int n = blockIdx.x * blockDim.x + threadIdx.x;
    if (n < N) inv_deg[n] = 1.0f / (float)max(deg[n], 1);
}

// ---------------- hierarchical exclusive scan (deg -> row_start) ----------------
__global__ void scan1_kernel(const int* __restrict__ deg, int N,
                             int* __restrict__ excl, int* __restrict__ bsums) {
    __shared__ int s[SCAN_B];
    int tid = threadIdx.x;
    int i = blockIdx.x * SCAN_B + tid;
    int v = (i < N) ? deg[i] : 0;
    s[tid] = v;
    __syncthreads();
    #pragma unroll
    for (int off = 1; off < SCAN_B; off <<= 1) {
        int t = (tid >= off) ? s[tid - off] : 0;
        __syncthreads();
        s[tid] += t;
        __syncthreads();
    }
    if (i <= N) excl[i] = s[tid] - v;
    if (tid == SCAN_B - 1) bsums[blockIdx.x] = s[tid];
}

__global__ void scan2_kernel(int* __restrict__ bsums, int nb) {
    __shared__ int s[SCAN_B];
    int tid = threadIdx.x;
    int v = (tid < nb) ? bsums[tid] : 0;
    s[tid] = v;
    __syncthreads();
    #pragma unroll
    for (int off = 1; off < SCAN_B; off <<= 1) {
        int t = (tid >= off) ? s[tid - off] : 0;
        __syncthreads();
        s[tid] += t;
        __syncthreads();
    }
    if (tid < nb) bsums[tid] = s[tid] - v;
}

__global__ void scan3_kernel(const int* __restrict__ excl, const int* __restrict__ bsums,
                             int N, int* __restrict__ row_start) {
    int i = blockIdx.x * SCAN_B + threadIdx.x;
    if (i <= N) row_start[i] = excl[i] + bsums[blockIdx.x];
}

// ---------------- CSR bucket fill ----------------
__global__ void fill_kernel(const int* __restrict__ src, const int* __restrict__ dst, int E,
                            const int* __restrict__ row_start, int* __restrict__ cursor,
                            int* __restrict__ csr_src) {
    int e = blockIdx.x * blockDim.x + threadIdx.x;
    if (e < E) {
        int d = dst[e];
        int pos = row_start[d] + atomicAdd(&cursor[d], 1);
        csr_src[pos] = src[e];
    }
}

// ---------------- W -> transposed bf16 hi/lo split (once per launch) ----------------
__global__ void wprep_kernel(const float* __restrict__ W,
                             unsigned short* __restrict__ Wt_hi,
                             unsigned short* __restrict__ Wt_lo) {
    int k = blockIdx.x;
    int n = threadIdx.x;
    float w = W[k * DIM + n];
    unsigned short hi = f32_to_bf16(w);
    float rem = w - bf16_to_f32(hi);
    Wt_hi[n * DIM + k] = hi;
    Wt_lo[n * DIM + k] = f32_to_bf16(rem);
}

// ---------------- x0 -> bf16 copy (layer-0 gather source) ----------------
__global__ void xprep_kernel(const float* __restrict__ x, unsigned short* __restrict__ xh, int n4) {
    int i = blockIdx.x * blockDim.x + threadIdx.x;
    if (i < n4) {
        float4 v = ((const float4*)x)[i];
        ushort4 o;
        o.x = f32_to_bf16(v.x); o.y = f32_to_bf16(v.y);
        o.z = f32_to_bf16(v.z); o.w = f32_to_bf16(v.w);
        ((ushort4*)xh)[i] = o;
    }
}

// ---------------- gather aggregation (bf16 src) + residual mix -> bf16 hi/lo h ----------------
// one 64-lane wave per node; lane owns 4 contiguous columns (8B loads).
__global__ __launch_bounds__(256) void aggregate_kernel(
    const unsigned short* __restrict__ xh, const float* __restrict__ x0,
    const int* __restrict__ row_start, const int* __restrict__ csr_src,
    const float* __restrict__ inv_deg,
    unsigned short* __restrict__ h_hi, unsigned short* __restrict__ h_lo, int N)
{
    int node = blockIdx.x * 4 + (threadIdx.x >> 6);
    if (node >= N) return;
    int c = (threadIdx.x & 63) * 4;

    int beg = row_start[node];
    int end = row_start[node + 1];

    float a0 = 0.f, a1 = 0.f, a2 = 0.f, a3 = 0.f;
    int e = beg;
    for (; e + 2 <= end; e += 2) {
        int s0 = csr_src[e];
        int s1 = csr_src[e + 1];
        ushort4 v0 = *(const ushort4*)(xh + (size_t)s0 * DIM + c);
        ushort4 v1 = *(const ushort4*)(xh + (size_t)s1 * DIM + c);
        a0 += bf16_to_f32(v0.x) + bf16_to_f32(v1.x);
        a1 += bf16_to_f32(v0.y) + bf16_to_f32(v1.y);
        a2 += bf16_to_f32(v0.z) + bf16_to_f32(v1.z);
        a3 += bf16_to_f32(v0.w) + bf16_to_f32(v1.w);
    }
    if (e < end) {
        int s0 = csr_src[e];
        ushort4 v0 = *(const ushort4*)(xh + (size_t)s0 * DIM + c);
        a0 += bf16_to_f32(v0.x);
        a1 += bf16_to_f32(v0.y);
        a2 += bf16_to_f32(v0.z);
        a3 += bf16_to_f32(v0.w);
    }

    float scale = (1.0f - ALPHA) * inv_deg[node];
    float4 xv = *(const float4*)(x0 + (size_t)node * DIM + c);
    float hv[4];
    hv[0] = ALPHA * xv.x + scale * a0;
    hv[1] = ALPHA * xv.y + scale * a1;
    hv[2] = ALPHA * xv.z + scale * a2;
    hv[3] = ALPHA * xv.w + scale * a3;

    ushort4 hi4, lo4;
    unsigned short* hip_ = &hi4.x;
    unsigned short* lop_ = &lo4.x;
    #pragma unroll
    for (int i = 0; i < 4; i++) {
        unsigned short hb = f32_to_bf16(hv[i]);
        hip_[i] = hb;
        lop_[i] = f32_to_bf16(hv[i] - bf16_to_f32(hb));
    }
    *(ushort4*)(h_hi + (size_t)node * DIM + c) = hi4;
    *(ushort4*)(h_lo + (size_t)node * DIM + c) = lo4;
}

// ---------------- MFMA GEMM: out = relu(h @ W), bf16x3 split precision ----------------
// 128x128 tile per 256-thread block; 4 waves in 2x2; each wave 4x4 frags of 16x16x32.
// LAST=true -> store fp32 to d_out; else store bf16 activations for next gather.
template <bool LAST>
__global__ __launch_bounds__(256) void gemm_mfma_kernel(
    const unsigned short* __restrict__ h_hi, const unsigned short* __restrict__ h_lo,
    const unsigned short* __restrict__ Wt_hi, const unsigned short* __restrict__ Wt_lo,
    float* __restrict__ out_f32, unsigned short* __restrict__ out_bf16, int N)
{
    __shared__ unsigned short As_hi[128 * 32];
    __shared__ unsigned short As_lo[128 * 32];
    __shared__ unsigned short Bs_hi[128 * 32];
    __shared__ unsigned short Bs_lo[128 * 32];

    const int t    = threadIdx.x;
    const int w    = t >> 6;
    const int lane = t & 63;
    const int lm   = lane & 15;
    const int q    = lane >> 4;
    const int wm   = w >> 1, wn = w & 1;
    const int m0   = blockIdx.x * 128;
    const int n0   = blockIdx.y * 128;

    const unsigned short* gsrc;
    unsigned short* lds;
    int row_base;
    if (w == 0)      { gsrc = h_hi;  lds = As_hi; row_base = m0; }
    else if (w == 1) { gsrc = h_lo;  lds = As_lo; row_base = m0; }
    else if (w == 2) { gsrc = Wt_hi; lds = Bs_hi; row_base = n0; }
    else             { gsrc = Wt_lo; lds = Bs_lo; row_base = n0; }
    const int rl = lane >> 2;
    const int g  = lane & 3;

    f32x4 acc[4][4];
    #pragma unroll
    for (int mi = 0; mi < 4; mi++)
        #pragma unroll
        for (int ni = 0; ni < 4; ni++)
            acc[mi][ni] = (f32x4){0.f, 0.f, 0.f, 0.f};

    for (int kb = 0; kb < DIM; kb += 32) {
        __syncthreads();
        #pragma unroll
        for (int j = 0; j < 8; j++) {
            int r = j * 16 + rl;
            const unsigned short* src = gsrc + (size_t)(row_base + r) * DIM + kb + g * 8;
            load_lds16(src, &lds[j * 512]);
        }
        __syncthreads();

        short8 a_hi[4], a_lo[4];
        #pragma unroll
        for (int mi = 0; mi < 4; mi++) {
            int row = wm * 64 + mi * 16 + lm;
            a_hi[mi] = *(const short8*)&As_hi[row * 32 + q * 8];
            a_lo[mi] = *(const short8*)&As_lo[row * 32 + q * 8];
        }
        #pragma unroll
        for (int ni = 0; ni < 4; ni++) {
            int row = wn * 64 + ni * 16 + lm;
            short8 b_hi = *(const short8*)&Bs_hi[row * 32 + q * 8];
            short8 b_lo = *(const short8*)&Bs_lo[row * 32 + q * 8];
            #pragma unroll
            for (int mi = 0; mi < 4; mi++) {
                acc[mi][ni] = __builtin_amdgcn_mfma_f32_16x16x32_bf16(a_hi[mi], b_hi, acc[mi][ni], 0, 0, 0);
                acc[mi][ni] = __builtin_amdgcn_mfma_f32_16x16x32_bf16(a_hi[mi], b_lo, acc[mi][ni], 0, 0, 0);
                acc[mi][ni] = __builtin_amdgcn_mfma_f32_16x16x32_bf16(a_lo[mi], b_hi, acc[mi][ni], 0, 0, 0);
            }
        }
    }

    // epilogue: C/D layout col=lane&15, row=q*4+reg
    #pragma unroll
    for (int mi = 0; mi < 4; mi++) {
        const int rowb = m0 + wm * 64 + mi * 16 + q * 4;
        #pragma unroll
        for (int ni = 0; ni < 4; ni++) {
            const int col = n0 + wn * 64 + ni * 16 + lm;
            #pragma unroll
            for (int r = 0; r < 4; r++) {
                int row = rowb + r;
                if (row < N) {
                    float v = fmaxf(acc[mi][ni][r], 0.0f);
                    if (LAST) out_f32[(size_t)row * DIM + col] = v;
                    else      out_bf16[(size_t)row * DIM + col] = f32_to_bf16(v);
                }
            }
        }
    }
}

extern "C" void kernel_launch(void* const* d_in, const int* in_sizes, int n_in,
                              void* d_out, int out_size, void* d_ws, size_t ws_size,
                              hipStream_t stream) {
    const float* x0  = (const float*)d_in[0];
    const int*   ei  = (const int*)d_in[1];
    const float* W   = (const float*)d_in[2];
    float*       out = (float*)d_out;

    const int N = in_sizes[0] / DIM;
    const int E = in_sizes[1] / 2;
    const int N_pad = (N + 127) & ~127;
    const int* src = ei;
    const int* dst = ei + E;

    const int nb = (N + 1 + SCAN_B - 1) / SCAN_B;

    char* ws = (char*)d_ws;
    size_t off = 0;
    auto alloc = [&](size_t bytes) { char* p = ws + off; off += (bytes + 15) & ~size_t(15); return p; };
    unsigned short* h_hi    = (unsigned short*)alloc((size_t)N_pad * DIM * 2);
    unsigned short* h_lo    = (unsigned short*)alloc((size_t)N_pad * DIM * 2);
    unsigned short* act     = (unsigned short*)alloc((size_t)N_pad * DIM * 2);  // bf16 activations
    unsigned short* Wt_hi   = (unsigned short*)alloc((size_t)DIM * DIM * 2);
    unsigned short* Wt_lo   = (unsigned short*)alloc((size_t)DIM * DIM * 2);
    float* inv_deg  = (float*)alloc((size_t)N * 4);
    int*   deg      = (int*)  alloc((size_t)N * 4);
    int*   row_start= (int*)  alloc((size_t)(N + 1) * 4);
    int*   excl     = (int*)  alloc((size_t)(N + 1) * 4);
    int*   cursor   = (int*)  alloc((size_t)N * 4);
    int*   bsums    = (int*)  alloc((size_t)nb * 4);
    int*   csr_src  = (int*)  alloc((size_t)E * 4);

    // ---- CSR build + W/x0 prep (per launch) ----
    hipMemsetAsync(deg, 0, (size_t)N * 4, stream);
    hipMemsetAsync(cursor, 0, (size_t)N * 4, stream);
    deg_kernel<<<(E + 255) / 256, 256, 0, stream>>>(dst, E, deg);
    invdeg_kernel<<<(N + 255) / 256, 256, 0, stream>>>(deg, N, inv_deg);
    scan1_kernel<<<nb, SCAN_B, 0, stream>>>(deg, N, excl, bsums);
    scan2_kernel<<<1, SCAN_B, 0, stream>>>(bsums, nb);
    scan3_kernel<<<nb, SCAN_B, 0, stream>>>(excl, bsums, N, row_start);
    fill_kernel<<<(E + 255) / 256, 256, 0, stream>>>(src, dst, E, row_start, cursor, csr_src);
    wprep_kernel<<<DIM, DIM, 0, stream>>>(W, Wt_hi, Wt_lo);
    const int n4 = N * DIM / 4;
    xprep_kernel<<<(n4 + 255) / 256, 256, 0, stream>>>(x0, act, n4);

    // ---- 5 GCN layers ----
    dim3 ggrid(N_pad / 128, 2);
    for (int layer = 0; layer < 5; layer++) {
        aggregate_kernel<<<(N + 3) / 4, 256, 0, stream>>>(act, x0, row_start, csr_src,
                                                          inv_deg, h_hi, h_lo, N);
        if (layer == 4)
            gemm_mfma_kernel<true><<<ggrid, 256, 0, stream>>>(h_hi, h_lo, Wt_hi, Wt_lo, out, nullptr, N);
        else
            gemm_mfma_kernel<false><<<ggrid, 256, 0, stream>>>(h_hi, h_lo, Wt_hi, Wt_lo, nullptr, act, N);
    }
}